// Round 1
// baseline (7758.054 us; speedup 1.0000x reference)
//
#include <hip/hip_runtime.h>
#include <hip/hip_bf16.h>

#define B_ 256
#define T_ 200
#define D_ 256
#define DK_ 64
#define H_ 4
#define BT_ (B_*T_)
#define DD_ (D_*D_)
#define ALPHA_ 0.5f

__device__ __forceinline__ float wave_sum(float v) {
#pragma unroll
    for (int o = 32; o >= 1; o >>= 1) v += __shfl_xor(v, o);
    return v;
}
__device__ __forceinline__ float wave_max(float v) {
#pragma unroll
    for (int o = 32; o >= 1; o >>= 1) v = fmaxf(v, __shfl_xor(v, o));
    return v;
}

// seqs[b,t,:] = item_table[idx]*sqrt(D) + pos_table[(idx!=0)?(t+1):0]
__global__ void embed_kernel(const int* __restrict__ ls,
                             const float* __restrict__ itab,
                             const float* __restrict__ ptab,
                             float* __restrict__ seqs) {
    int bt = blockIdx.x;
    int t = bt % T_;
    int lane = threadIdx.x;          // 64 lanes, 4 floats each
    int idx = ls[bt];
    int pos = idx ? (t + 1) : 0;
    float4 a = ((const float4*)(itab + (size_t)idx * D_))[lane];
    float4 p = ((const float4*)(ptab + (size_t)pos * D_))[lane];
    float4 r = { a.x*16.f+p.x, a.y*16.f+p.y, a.z*16.f+p.z, a.w*16.f+p.w };
    ((float4*)(seqs + (size_t)bt * D_))[lane] = r;
}

// Y = (x - mean)/sqrt(var + 1e-8) * sc + bi   (one wave per row of 256)
__global__ void ln_kernel(const float* __restrict__ X, const float* __restrict__ sc,
                          const float* __restrict__ bi, float* __restrict__ Y) {
    int row = blockIdx.x, lane = threadIdx.x;
    float4 x = ((const float4*)(X + (size_t)row * D_))[lane];
    float m = wave_sum(x.x + x.y + x.z + x.w) * (1.f / D_);
    float d0 = x.x - m, d1 = x.y - m, d2 = x.z - m, d3 = x.w - m;
    float v = wave_sum(d0*d0 + d1*d1 + d2*d2 + d3*d3) * (1.f / D_);
    float inv = rsqrtf(v + 1e-8f);
    float4 s4 = ((const float4*)sc)[lane];
    float4 b4 = ((const float4*)bi)[lane];
    float4 r = { d0*inv*s4.x + b4.x, d1*inv*s4.y + b4.y,
                 d2*inv*s4.z + b4.z, d3*inv*s4.w + b4.w };
    ((float4*)(Y + (size_t)row * D_))[lane] = r;
}

// C[M,256] = A[M,256] @ W[256,256] + bias (+res) (relu) ; M = BT_, 64x64 tile
template<bool RELU, bool RES>
__global__ __launch_bounds__(256) void gemm_kernel(
    const float* __restrict__ A, const float* __restrict__ W,
    const float* __restrict__ bias, const float* __restrict__ res,
    float* __restrict__ C) {
    __shared__ float As[16][65];   // [k][m]
    __shared__ float Ws[16][65];   // [k][n]
    int m0 = blockIdx.y * 64;
    int n0 = blockIdx.x * 64;
    int t = threadIdx.x;
    int tx = t & 15, ty = t >> 4;
    float acc[4][4] = {};
    for (int k0 = 0; k0 < D_; k0 += 16) {
        {   // A tile: 64 rows x 16 cols
            int r = t >> 2, c4 = (t & 3) * 4;
            float4 a = *(const float4*)(A + (size_t)(m0 + r) * D_ + k0 + c4);
            As[c4+0][r] = a.x; As[c4+1][r] = a.y; As[c4+2][r] = a.z; As[c4+3][r] = a.w;
        }
        {   // W tile: 16 rows x 64 cols
            int r = t >> 4, c4 = (t & 15) * 4;
            float4 w = *(const float4*)(W + (size_t)(k0 + r) * D_ + n0 + c4);
            Ws[r][c4+0] = w.x; Ws[r][c4+1] = w.y; Ws[r][c4+2] = w.z; Ws[r][c4+3] = w.w;
        }
        __syncthreads();
#pragma unroll
        for (int kk = 0; kk < 16; ++kk) {
            float a0 = As[kk][ty*4+0], a1 = As[kk][ty*4+1],
                  a2 = As[kk][ty*4+2], a3 = As[kk][ty*4+3];
            float w0 = Ws[kk][tx*4+0], w1 = Ws[kk][tx*4+1],
                  w2 = Ws[kk][tx*4+2], w3 = Ws[kk][tx*4+3];
            acc[0][0] += a0*w0; acc[0][1] += a0*w1; acc[0][2] += a0*w2; acc[0][3] += a0*w3;
            acc[1][0] += a1*w0; acc[1][1] += a1*w1; acc[1][2] += a1*w2; acc[1][3] += a1*w3;
            acc[2][0] += a2*w0; acc[2][1] += a2*w1; acc[2][2] += a2*w2; acc[2][3] += a2*w3;
            acc[3][0] += a3*w0; acc[3][1] += a3*w1; acc[3][2] += a3*w2; acc[3][3] += a3*w3;
        }
        __syncthreads();
    }
#pragma unroll
    for (int i = 0; i < 4; ++i) {
        int m = m0 + ty*4 + i;
#pragma unroll
        for (int j = 0; j < 4; ++j) {
            int n = n0 + tx*4 + j;
            float v = acc[i][j] + bias[n];
            if (RES) v += res[(size_t)m * D_ + n];
            if (RELU) v = fmaxf(v, 0.f);
            C[(size_t)m * D_ + n] = v;
        }
    }
}

// fused attention: one wave per (b,h,q-row). scores -> mask -> (cm mult) -> softmax -> PV
template<bool DEC>
__global__ __launch_bounds__(64) void attn_kernel(
    const float* __restrict__ q, const float* __restrict__ k,
    const float* __restrict__ v, const float* __restrict__ cm,
    float* __restrict__ o) {
    int qrow = blockIdx.x;
    int h = blockIdx.y;
    int b = blockIdx.z;
    int lane = threadIdx.x;
    __shared__ float qs[DK_];
    __shared__ float ps[256];
    size_t base = (size_t)b * T_ * D_ + (size_t)h * DK_;
    qs[lane] = q[base + (size_t)qrow * D_ + lane];
    __syncthreads();
    float sc[4];
    float mx = -1e38f;
#pragma unroll
    for (int j = 0; j < 4; ++j) {
        int kk = lane + j * 64;
        float sv = -1e38f;
        if (kk < T_) {
            const float4* k4 = (const float4*)(k + base + (size_t)kk * D_);
            const float4* q4 = (const float4*)qs;
            float dot = 0.f;
#pragma unroll
            for (int d = 0; d < DK_/4; ++d) {
                float4 kv = k4[d], qv = q4[d];
                dot += qv.x*kv.x + qv.y*kv.y + qv.z*kv.z + qv.w*kv.w;
            }
            sv = dot * 0.125f;                 // 1/sqrt(64)
            if (kk > qrow) sv = -1e9f;         // mask BEFORE reweight (as reference)
            if (DEC) sv *= (1.0f + ALPHA_ * cm[((size_t)b * T_ + qrow) * T_ + kk]);
        }
        sc[j] = sv;
        mx = fmaxf(mx, sv);
    }
    mx = wave_max(mx);
    float sum = 0.f;
#pragma unroll
    for (int j = 0; j < 4; ++j) {
        int kk = lane + j * 64;
        float e = (kk < T_) ? __expf(sc[j] - mx) : 0.f;
        sc[j] = e;
        sum += e;
    }
    sum = wave_sum(sum);
    float inv = 1.f / sum;
#pragma unroll
    for (int j = 0; j < 4; ++j) {
        int kk = lane + j * 64;
        if (kk < T_) ps[kk] = sc[j] * inv;
    }
    __syncthreads();
    float out = 0.f;
    for (int kk = 0; kk < T_; ++kk)
        out += ps[kk] * v[base + (size_t)kk * D_ + lane];
    o[base + (size_t)qrow * D_ + lane] = out;
}

__global__ void rowmean_kernel(const float* __restrict__ Z, float* __restrict__ m) {
    int row = blockIdx.x, lane = threadIdx.x;
    float4 x = ((const float4*)(Z + (size_t)row * D_))[lane];
    float s = wave_sum(x.x + x.y + x.z + x.w);
    if (lane == 0) m[row] = s * (1.f / D_);
}

// cm[b,t,s] = min( sum_d (z[t,d]-m_t)(z[s,d]-m_s) / 255, 3.0 )
__global__ __launch_bounds__(256) void cov_kernel(const float* __restrict__ Z,
                                                  const float* __restrict__ m,
                                                  float* __restrict__ cm) {
    int b = blockIdx.z;
    int t0 = blockIdx.y * 16, s0 = blockIdx.x * 16;
    int tx = threadIdx.x, ty = threadIdx.y;
    __shared__ float St[16][17], Ss[16][17];
    float acc = 0.f;
    for (int d0 = 0; d0 < D_; d0 += 16) {
        int tr = t0 + ty;
        St[ty][tx] = (tr < T_) ? (Z[((size_t)b*T_ + tr) * D_ + d0 + tx] - m[b*T_ + tr]) : 0.f;
        int sr = s0 + ty;
        Ss[ty][tx] = (sr < T_) ? (Z[((size_t)b*T_ + sr) * D_ + d0 + tx] - m[b*T_ + sr]) : 0.f;
        __syncthreads();
#pragma unroll
        for (int dd = 0; dd < 16; ++dd) acc += St[ty][dd] * Ss[tx][dd];
        __syncthreads();
    }
    int t = t0 + ty, s = s0 + tx;
    if (t < T_ && s < T_)
        cm[((size_t)b*T_ + t) * T_ + s] = fminf(acc * (1.f/255.f), 3.0f);
}

extern "C" void kernel_launch(void* const* d_in, const int* in_sizes, int n_in,
                              void* d_out, int out_size, void* d_ws, size_t ws_size,
                              hipStream_t stream) {
    const int*   log_seqs = (const int*)  d_in[0];
    const float* item_tab = (const float*)d_in[1];
    const float* pos_tab  = (const float*)d_in[2];
    const float* ln1_s = (const float*)d_in[3];
    const float* ln1_b = (const float*)d_in[4];
    const float* Wq = (const float*)d_in[5];
    const float* bq = (const float*)d_in[6];
    const float* Wk = (const float*)d_in[7];
    const float* bk = (const float*)d_in[8];
    const float* Wv = (const float*)d_in[9];
    const float* bv = (const float*)d_in[10];
    const float* Wo = (const float*)d_in[11];
    const float* bo = (const float*)d_in[12];
    const float* ln2_s = (const float*)d_in[13];
    const float* ln2_b = (const float*)d_in[14];
    const float* W1 = (const float*)d_in[15];
    const float* b1 = (const float*)d_in[16];
    const float* W2 = (const float*)d_in[17];
    const float* b2 = (const float*)d_in[18];
    const float* last_s = (const float*)d_in[19];
    const float* last_b = (const float*)d_in[20];

    float* ws = (float*)d_ws;
    const size_t NTD = (size_t)BT_ * D_;
    float* s0    = ws;              // seqs  (layer-3 output reuses this)
    float* s1    = s0 + NTD;        // causal_z / layer-2 output
    float* Qn    = s1 + NTD;
    float* qb    = Qn + NTD;        // q, then s (attn residual sum)
    float* kb    = qb + NTD;        // k, then y
    float* vb    = kb + NTD;        // v, then ffn tmp
    float* at    = vb + NTD;        // attention output
    float* cmask = at + NTD;        // B*T*T
    float* rmean = cmask + (size_t)B_ * T_ * T_;

    dim3 gg(D_/64, BT_/64);

    auto encoder = [&](const float* X, float* OUT, int i, const float* cm) {
        ln_kernel<<<BT_, 64, 0, stream>>>(X, ln1_s + i*D_, ln1_b + i*D_, Qn);
        gemm_kernel<false,false><<<gg, 256, 0, stream>>>(Qn, Wq + (size_t)i*DD_, bq + i*D_, nullptr, qb);
        gemm_kernel<false,false><<<gg, 256, 0, stream>>>(X,  Wk + (size_t)i*DD_, bk + i*D_, nullptr, kb);
        gemm_kernel<false,false><<<gg, 256, 0, stream>>>(X,  Wv + (size_t)i*DD_, bv + i*D_, nullptr, vb);
        if (cm) attn_kernel<true ><<<dim3(T_,H_,B_), 64, 0, stream>>>(qb, kb, vb, cm, at);
        else    attn_kernel<false><<<dim3(T_,H_,B_), 64, 0, stream>>>(qb, kb, vb, nullptr, at);
        // s = Qn + at@Wo + bo   -> qb
        gemm_kernel<false,true><<<gg, 256, 0, stream>>>(at, Wo + (size_t)i*DD_, bo + i*D_, Qn, qb);
        // y = LN(s)             -> kb
        ln_kernel<<<BT_, 64, 0, stream>>>(qb, ln2_s + i*D_, ln2_b + i*D_, kb);
        // tmp = relu(y@W1+b1)   -> vb
        gemm_kernel<true,false><<<gg, 256, 0, stream>>>(kb, W1 + (size_t)i*DD_, b1 + i*D_, nullptr, vb);
        // out = tmp@W2+b2 + y
        gemm_kernel<false,true><<<gg, 256, 0, stream>>>(vb, W2 + (size_t)i*DD_, b2 + i*D_, kb, OUT);
    };

    embed_kernel<<<BT_, 64, 0, stream>>>(log_seqs, item_tab, pos_tab, s0);

    // causal loop applies each layer to ORIGINAL seqs -> only layer L/2-1 = 1 survives
    encoder(s0, s1, 1, nullptr);

    rowmean_kernel<<<BT_, 64, 0, stream>>>(s1, rmean);
    cov_kernel<<<dim3((T_+15)/16, (T_+15)/16, B_), dim3(16,16), 0, stream>>>(s1, rmean, cmask);

    encoder(s0, s1, 2, cmask);
    encoder(s1, s0, 3, cmask);

    ln_kernel<<<BT_, 64, 0, stream>>>(s0, last_s, last_b, (float*)d_out);
}

// Round 4
// 3509.297 us; speedup vs baseline: 2.2107x; 2.2107x over previous
//
#include <hip/hip_runtime.h>
#include <hip/hip_bf16.h>

#define B_ 256
#define T_ 200
#define D_ 256
#define H_ 4
#define BT_ (B_*T_)
#define DD_ (D_*D_)
#define KS_S 72    // Ks stride (elems): 144B row pitch = 9*16B
#define VT_S 232   // Vt/Ps stride (elems): 464B = 29*16B; kpos padded 200..231 with zeros

typedef __attribute__((ext_vector_type(4))) float  f32x4;
typedef __attribute__((ext_vector_type(8))) __bf16 bf16x8;

union frag8 { unsigned u[4]; bf16x8 v; };

__device__ __forceinline__ unsigned short f2bf(float f) {
    unsigned u = __float_as_uint(f);
    u += 0x7FFFu + ((u >> 16) & 1u);          // RNE to bf16
    return (unsigned short)(u >> 16);
}
__device__ __forceinline__ unsigned pk2(float lo, float hi) {
    return (unsigned)f2bf(lo) | ((unsigned)f2bf(hi) << 16);
}

__device__ __forceinline__ float wave_sum(float v) {
#pragma unroll
    for (int o = 32; o >= 1; o >>= 1) v += __shfl_xor(v, o);
    return v;
}

// ---------------- embed ----------------
__global__ void embed_kernel(const int* __restrict__ ls,
                             const float* __restrict__ itab,
                             const float* __restrict__ ptab,
                             float* __restrict__ seqs) {
    int bt = blockIdx.x;
    int t = bt % T_;
    int lane = threadIdx.x;
    int idx = ls[bt];
    int pos = idx ? (t + 1) : 0;
    float4 a = ((const float4*)(itab + (size_t)idx * D_))[lane];
    float4 p = ((const float4*)(ptab + (size_t)pos * D_))[lane];
    float4 r = { a.x*16.f+p.x, a.y*16.f+p.y, a.z*16.f+p.z, a.w*16.f+p.w };
    ((float4*)(seqs + (size_t)bt * D_))[lane] = r;
}

// ---------------- layernorm ----------------
__global__ void ln_kernel(const float* __restrict__ X, const float* __restrict__ sc,
                          const float* __restrict__ bi, float* __restrict__ Y) {
    int row = blockIdx.x, lane = threadIdx.x;
    float4 x = ((const float4*)(X + (size_t)row * D_))[lane];
    float m = wave_sum(x.x + x.y + x.z + x.w) * (1.f / D_);
    float d0 = x.x - m, d1 = x.y - m, d2 = x.z - m, d3 = x.w - m;
    float v = wave_sum(d0*d0 + d1*d1 + d2*d2 + d3*d3) * (1.f / D_);
    float inv = rsqrtf(v + 1e-8f);
    float4 s4 = ((const float4*)sc)[lane];
    float4 b4 = ((const float4*)bi)[lane];
    float4 r = { d0*inv*s4.x + b4.x, d1*inv*s4.y + b4.y,
                 d2*inv*s4.z + b4.z, d3*inv*s4.w + b4.w };
    ((float4*)(Y + (size_t)row * D_))[lane] = r;
}

// ---------------- fp32 GEMM (unchanged; MFMA conversion next round) ----------------
template<bool RELU, bool RES>
__global__ __launch_bounds__(256) void gemm_kernel(
    const float* __restrict__ A, const float* __restrict__ W,
    const float* __restrict__ bias, const float* __restrict__ res,
    float* __restrict__ C) {
    __shared__ float As[16][65];
    __shared__ float Ws[16][65];
    int m0 = blockIdx.y * 64;
    int n0 = blockIdx.x * 64;
    int t = threadIdx.x;
    int tx = t & 15, ty = t >> 4;
    float acc[4][4] = {};
    for (int k0 = 0; k0 < D_; k0 += 16) {
        {
            int r = t >> 2, c4 = (t & 3) * 4;
            float4 a = *(const float4*)(A + (size_t)(m0 + r) * D_ + k0 + c4);
            As[c4+0][r] = a.x; As[c4+1][r] = a.y; As[c4+2][r] = a.z; As[c4+3][r] = a.w;
        }
        {
            int r = t >> 4, c4 = (t & 15) * 4;
            float4 w = *(const float4*)(W + (size_t)(k0 + r) * D_ + n0 + c4);
            Ws[r][c4+0] = w.x; Ws[r][c4+1] = w.y; Ws[r][c4+2] = w.z; Ws[r][c4+3] = w.w;
        }
        __syncthreads();
#pragma unroll
        for (int kk = 0; kk < 16; ++kk) {
            float a0 = As[kk][ty*4+0], a1 = As[kk][ty*4+1],
                  a2 = As[kk][ty*4+2], a3 = As[kk][ty*4+3];
            float w0 = Ws[kk][tx*4+0], w1 = Ws[kk][tx*4+1],
                  w2 = Ws[kk][tx*4+2], w3 = Ws[kk][tx*4+3];
            acc[0][0] += a0*w0; acc[0][1] += a0*w1; acc[0][2] += a0*w2; acc[0][3] += a0*w3;
            acc[1][0] += a1*w0; acc[1][1] += a1*w1; acc[1][2] += a1*w2; acc[1][3] += a1*w3;
            acc[2][0] += a2*w0; acc[2][1] += a2*w1; acc[2][2] += a2*w2; acc[2][3] += a2*w3;
            acc[3][0] += a3*w0; acc[3][1] += a3*w1; acc[3][2] += a3*w2; acc[3][3] += a3*w3;
        }
        __syncthreads();
    }
#pragma unroll
    for (int i = 0; i < 4; ++i) {
        int m = m0 + ty*4 + i;
#pragma unroll
        for (int j = 0; j < 4; ++j) {
            int n = n0 + tx*4 + j;
            float v = acc[i][j] + bias[n];
            if (RES) v += res[(size_t)m * D_ + n];
            if (RELU) v = fmaxf(v, 0.f);
            C[(size_t)m * D_ + n] = v;
        }
    }
}

// ---------------- MFMA attention ----------------
// one block per (h, b). K (row-major) and V^T staged in padded-stride bf16 LDS;
// 4 waves x 16-row q-tiles; causal tile skipping. MFMA via builtins (hazard-safe).
template<bool DEC>
__global__ __launch_bounds__(256) void attn_mfma(
    const float* __restrict__ q, const float* __restrict__ k,
    const float* __restrict__ v, const float* __restrict__ cm,
    float* __restrict__ o) {
    __shared__ unsigned short Ks[208 * KS_S];    // [kpos][dk]
    __shared__ unsigned short Vt[64 * VT_S];     // [dk][kpos]
    __shared__ unsigned short Ps[4 * 16 * VT_S]; // per-wave [qrow][kpos]
    int h = blockIdx.x, b = blockIdx.y;
    int tid = threadIdx.x, lane = tid & 63, wv = tid >> 6;
    int l15 = lane & 15, l4 = lane >> 4;
    size_t base = (size_t)(b * T_) * D_ + h * 64;

    // stage K -> Ks (bf16), V -> Vt (transposed bf16)
    for (int i = tid; i < T_ * 16; i += 256) {
        int r = i >> 4, c4 = (i & 15) << 2;
        float4 kv = *(const float4*)(k + base + (size_t)r * D_ + c4);
        int idx = r * KS_S + c4;
        *(unsigned*)&Ks[idx]     = pk2(kv.x, kv.y);
        *(unsigned*)&Ks[idx + 2] = pk2(kv.z, kv.w);
        float4 vv = *(const float4*)(v + base + (size_t)r * D_ + c4);
        Vt[(c4 + 0) * VT_S + r] = f2bf(vv.x);
        Vt[(c4 + 1) * VT_S + r] = f2bf(vv.y);
        Vt[(c4 + 2) * VT_S + r] = f2bf(vv.z);
        Vt[(c4 + 3) * VT_S + r] = f2bf(vv.w);
    }
    // zero pads: K rows 200..207; V^T cols 200..231; Ps cols 208..231 (never re-written)
    for (int i = tid; i < 8 * KS_S; i += 256) Ks[200 * KS_S + i] = 0;
    for (int i = tid; i < 64 * 32; i += 256) Vt[(i >> 5) * VT_S + 200 + (i & 31)] = 0;
    for (int i = tid; i < 64 * 24; i += 256) Ps[(i / 24) * VT_S + 208 + (i % 24)] = 0;
    __syncthreads();

    unsigned short* pw = &Ps[wv * 16 * VT_S];
    const f32x4 zero = {0.f, 0.f, 0.f, 0.f};

    for (int qt = wv; qt < 13; qt += 4) {
        int q0 = qt * 16;
        // Q fragments (A operand): row = l15, k(d) = l4*8 + j (+32 for frag1)
        int qrow = q0 + l15;
        int qrc = qrow < T_ ? qrow : T_ - 1;
        const float* qp = q + base + (size_t)qrc * D_ + l4 * 8;
        float4 qa = *(const float4*)qp;
        float4 qb4 = *(const float4*)(qp + 4);
        float4 qc = *(const float4*)(qp + 32);
        float4 qd = *(const float4*)(qp + 36);
        frag8 aq0, aq1;
        aq0.u[0] = pk2(qa.x, qa.y);  aq0.u[1] = pk2(qa.z, qa.w);
        aq0.u[2] = pk2(qb4.x, qb4.y); aq0.u[3] = pk2(qb4.z, qb4.w);
        aq1.u[0] = pk2(qc.x, qc.y);  aq1.u[1] = pk2(qc.z, qc.w);
        aq1.u[2] = pk2(qd.x, qd.y);  aq1.u[3] = pk2(qd.z, qd.w);

        f32x4 S[13];
        float mx[4] = {-3e38f, -3e38f, -3e38f, -3e38f};
#pragma unroll
        for (int kt = 0; kt < 13; ++kt) {
            if (kt <= qt) {
                bf16x8 b0 = *(const bf16x8*)&Ks[(kt * 16 + l15) * KS_S + l4 * 8];
                bf16x8 b1 = *(const bf16x8*)&Ks[(kt * 16 + l15) * KS_S + 32 + l4 * 8];
                f32x4 acc = __builtin_amdgcn_mfma_f32_16x16x32_bf16(aq0.v, b0, zero, 0, 0, 0);
                acc = __builtin_amdgcn_mfma_f32_16x16x32_bf16(aq1.v, b1, acc, 0, 0, 0);
                f32x4 sv;
#pragma unroll
                for (int i = 0; i < 4; ++i) {
                    int kk = kt * 16 + l15;
                    int qr = q0 + l4 * 4 + i;
                    float s = acc[i] * 0.125f;
                    bool valid = (qr < T_) && (kk < T_);
                    if (!valid) s = -1e9f;
                    else {
                        if (kk > qr) s = -1e9f;  // mask BEFORE cm multiply (as reference)
                        if (DEC) s *= (1.0f + 0.5f * cm[((size_t)(b * T_) + qr) * T_ + kk]);
                    }
                    sv[i] = s;
                    mx[i] = fmaxf(mx[i], s);
                }
                S[kt] = sv;
            }
        }
#pragma unroll
        for (int i = 0; i < 4; ++i) {
            float m = mx[i];
            m = fmaxf(m, __shfl_xor(m, 1));
            m = fmaxf(m, __shfl_xor(m, 2));
            m = fmaxf(m, __shfl_xor(m, 4));
            m = fmaxf(m, __shfl_xor(m, 8));
            mx[i] = m;
        }
        float sum[4] = {0.f, 0.f, 0.f, 0.f};
#pragma unroll
        for (int kt = 0; kt < 13; ++kt) {
            if (kt <= qt) {
#pragma unroll
                for (int i = 0; i < 4; ++i) {
                    float e = __expf(S[kt][i] - mx[i]);
                    S[kt][i] = e;
                    sum[i] += e;
                }
            }
        }
#pragma unroll
        for (int i = 0; i < 4; ++i) {
            float s = sum[i];
            s += __shfl_xor(s, 1);
            s += __shfl_xor(s, 2);
            s += __shfl_xor(s, 4);
            s += __shfl_xor(s, 8);
            sum[i] = 1.f / s;
        }
        // write normalized P (bf16); masked tiles written as 0
#pragma unroll
        for (int kt = 0; kt < 13; ++kt) {
#pragma unroll
            for (int i = 0; i < 4; ++i)
                pw[(l4 * 4 + i) * VT_S + kt * 16 + l15] =
                    (kt <= qt) ? f2bf(S[kt][i] * sum[i]) : (unsigned short)0;
        }

        // PV: O[16][64] = P[16][<=224] @ V[<=224][64], 7x K=32 max (pad cols are 0)
        int lastcol = q0 + 15;
        int npv32 = (lastcol >> 5) + 1; if (npv32 > 7) npv32 = 7;
        bf16x8 pa[7];
#pragma unroll
        for (int t = 0; t < 7; ++t)
            if (t < npv32)
                pa[t] = *(const bf16x8*)&pw[l15 * VT_S + t * 32 + l4 * 8];

        f32x4 O[4];
#pragma unroll
        for (int dt = 0; dt < 4; ++dt) {
            f32x4 acc = zero;
#pragma unroll
            for (int t = 0; t < 7; ++t) {
                if (t < npv32) {
                    bf16x8 vb = *(const bf16x8*)&Vt[(dt * 16 + l15) * VT_S + t * 32 + l4 * 8];
                    acc = __builtin_amdgcn_mfma_f32_16x16x32_bf16(pa[t], vb, acc, 0, 0, 0);
                }
            }
            O[dt] = acc;
        }
#pragma unroll
        for (int dt = 0; dt < 4; ++dt) {
#pragma unroll
            for (int i = 0; i < 4; ++i) {
                int qr = q0 + l4 * 4 + i;
                if (qr < T_)
                    o[base + (size_t)qr * D_ + dt * 16 + l15] = O[dt][i];
            }
        }
    }
}

// ---------------- cov mask ----------------
__global__ void rowmean_kernel(const float* __restrict__ Z, float* __restrict__ m) {
    int row = blockIdx.x, lane = threadIdx.x;
    float4 x = ((const float4*)(Z + (size_t)row * D_))[lane];
    float s = wave_sum(x.x + x.y + x.z + x.w);
    if (lane == 0) m[row] = s * (1.f / D_);
}

__global__ __launch_bounds__(256) void cov_kernel(const float* __restrict__ Z,
                                                  const float* __restrict__ m,
                                                  float* __restrict__ cm) {
    int b = blockIdx.z;
    int t0 = blockIdx.y * 16, s0 = blockIdx.x * 16;
    int tx = threadIdx.x, ty = threadIdx.y;
    __shared__ float St[16][17], Ss[16][17];
    float acc = 0.f;
    for (int d0 = 0; d0 < D_; d0 += 16) {
        int tr = t0 + ty;
        St[ty][tx] = (tr < T_) ? (Z[((size_t)b*T_ + tr) * D_ + d0 + tx] - m[b*T_ + tr]) : 0.f;
        int sr = s0 + ty;
        Ss[ty][tx] = (sr < T_) ? (Z[((size_t)b*T_ + sr) * D_ + d0 + tx] - m[b*T_ + sr]) : 0.f;
        __syncthreads();
#pragma unroll
        for (int dd = 0; dd < 16; ++dd) acc += St[ty][dd] * Ss[tx][dd];
        __syncthreads();
    }
    int t = t0 + ty, s = s0 + tx;
    if (t < T_ && s < T_)
        cm[((size_t)b*T_ + t) * T_ + s] = fminf(acc * (1.f/255.f), 3.0f);
}

extern "C" void kernel_launch(void* const* d_in, const int* in_sizes, int n_in,
                              void* d_out, int out_size, void* d_ws, size_t ws_size,
                              hipStream_t stream) {
    const int*   log_seqs = (const int*)  d_in[0];
    const float* item_tab = (const float*)d_in[1];
    const float* pos_tab  = (const float*)d_in[2];
    const float* ln1_s = (const float*)d_in[3];
    const float* ln1_b = (const float*)d_in[4];
    const float* Wq = (const float*)d_in[5];
    const float* bq = (const float*)d_in[6];
    const float* Wk = (const float*)d_in[7];
    const float* bk = (const float*)d_in[8];
    const float* Wv = (const float*)d_in[9];
    const float* bv = (const float*)d_in[10];
    const float* Wo = (const float*)d_in[11];
    const float* bo = (const float*)d_in[12];
    const float* ln2_s = (const float*)d_in[13];
    const float* ln2_b = (const float*)d_in[14];
    const float* W1 = (const float*)d_in[15];
    const float* b1 = (const float*)d_in[16];
    const float* W2 = (const float*)d_in[17];
    const float* b2 = (const float*)d_in[18];
    const float* last_s = (const float*)d_in[19];
    const float* last_b = (const float*)d_in[20];

    float* ws = (float*)d_ws;
    const size_t NTD = (size_t)BT_ * D_;
    float* s0    = ws;
    float* s1    = s0 + NTD;
    float* Qn    = s1 + NTD;
    float* qb    = Qn + NTD;
    float* kb    = qb + NTD;
    float* vb    = kb + NTD;
    float* at    = vb + NTD;
    float* cmask = at + NTD;
    float* rmean = cmask + (size_t)B_ * T_ * T_;

    dim3 gg(D_/64, BT_/64);

    auto encoder = [&](const float* X, float* OUT, int i, const float* cmp) {
        ln_kernel<<<BT_, 64, 0, stream>>>(X, ln1_s + i*D_, ln1_b + i*D_, Qn);
        gemm_kernel<false,false><<<gg, 256, 0, stream>>>(Qn, Wq + (size_t)i*DD_, bq + i*D_, nullptr, qb);
        gemm_kernel<false,false><<<gg, 256, 0, stream>>>(X,  Wk + (size_t)i*DD_, bk + i*D_, nullptr, kb);
        gemm_kernel<false,false><<<gg, 256, 0, stream>>>(X,  Wv + (size_t)i*DD_, bv + i*D_, nullptr, vb);
        if (cmp) attn_mfma<true ><<<dim3(H_, B_), 256, 0, stream>>>(qb, kb, vb, cmp, at);
        else     attn_mfma<false><<<dim3(H_, B_), 256, 0, stream>>>(qb, kb, vb, nullptr, at);
        gemm_kernel<false,true><<<gg, 256, 0, stream>>>(at, Wo + (size_t)i*DD_, bo + i*D_, Qn, qb);
        ln_kernel<<<BT_, 64, 0, stream>>>(qb, ln2_s + i*D_, ln2_b + i*D_, kb);
        gemm_kernel<true,false><<<gg, 256, 0, stream>>>(kb, W1 + (size_t)i*DD_, b1 + i*D_, nullptr, vb);
        gemm_kernel<false,true><<<gg, 256, 0, stream>>>(vb, W2 + (size_t)i*DD_, b2 + i*D_, kb, OUT);
    };

    embed_kernel<<<BT_, 64, 0, stream>>>(log_seqs, item_tab, pos_tab, s0);

    // causal loop applies each layer to ORIGINAL seqs -> only layer 1 survives
    encoder(s0, s1, 1, nullptr);

    rowmean_kernel<<<BT_, 64, 0, stream>>>(s1, rmean);
    cov_kernel<<<dim3((T_+15)/16, (T_+15)/16, B_), dim3(16,16), 0, stream>>>(s1, rmean, cmask);

    encoder(s0, s1, 2, cmask);
    encoder(s1, s0, 3, cmask);

    ln_kernel<<<BT_, 64, 0, stream>>>(s0, last_s, last_b, (float*)d_out);
}

// Round 6
// 1333.857 us; speedup vs baseline: 5.8163x; 2.6309x over previous
//
#include <hip/hip_runtime.h>
#include <hip/hip_bf16.h>

#define B_ 256
#define T_ 200
#define D_ 256
#define H_ 4
#define BT_ (B_*T_)
#define DD_ (D_*D_)
#define KS_S 72    // attn Ks stride
#define VT_S 232   // attn Vt/Ps stride
#define GS_ 72     // gemm LDS stride (64 + 8 pad): 144B row pitch, conflict-free
#define ZS_ 264    // cov Zb stride (256 + 8 pad): 528B row pitch, conflict-free

typedef __attribute__((ext_vector_type(4))) float  f32x4;
typedef __attribute__((ext_vector_type(8))) __bf16 bf16x8;
typedef __attribute__((ext_vector_type(4))) int    i32x4;

union frag8 { unsigned u[4]; bf16x8 v; };

__device__ __forceinline__ unsigned short f2bf(float f) {
    unsigned u = __float_as_uint(f);
    u += 0x7FFFu + ((u >> 16) & 1u);          // RNE to bf16
    return (unsigned short)(u >> 16);
}
__device__ __forceinline__ unsigned pk2(float lo, float hi) {
    return (unsigned)f2bf(lo) | ((unsigned)f2bf(hi) << 16);
}

__device__ __forceinline__ float wave_sum(float v) {
#pragma unroll
    for (int o = 32; o >= 1; o >>= 1) v += __shfl_xor(v, o);
    return v;
}

// ---------------- embed ----------------
__global__ void embed_kernel(const int* __restrict__ ls,
                             const float* __restrict__ itab,
                             const float* __restrict__ ptab,
                             float* __restrict__ seqs) {
    int bt = blockIdx.x;
    int t = bt % T_;
    int lane = threadIdx.x;
    int idx = ls[bt];
    int pos = idx ? (t + 1) : 0;
    float4 a = ((const float4*)(itab + (size_t)idx * D_))[lane];
    float4 p = ((const float4*)(ptab + (size_t)pos * D_))[lane];
    float4 r = { a.x*16.f+p.x, a.y*16.f+p.y, a.z*16.f+p.z, a.w*16.f+p.w };
    ((float4*)(seqs + (size_t)bt * D_))[lane] = r;
}

// ---------------- layernorm ----------------
__global__ void ln_kernel(const float* __restrict__ X, const float* __restrict__ sc,
                          const float* __restrict__ bi, float* __restrict__ Y) {
    int row = blockIdx.x, lane = threadIdx.x;
    float4 x = ((const float4*)(X + (size_t)row * D_))[lane];
    float m = wave_sum(x.x + x.y + x.z + x.w) * (1.f / D_);
    float d0 = x.x - m, d1 = x.y - m, d2 = x.z - m, d3 = x.w - m;
    float v = wave_sum(d0*d0 + d1*d1 + d2*d2 + d3*d3) * (1.f / D_);
    float inv = rsqrtf(v + 1e-8f);
    float4 s4 = ((const float4*)sc)[lane];
    float4 b4 = ((const float4*)bi)[lane];
    float4 r = { d0*inv*s4.x + b4.x, d1*inv*s4.y + b4.y,
                 d2*inv*s4.z + b4.z, d3*inv*s4.w + b4.w };
    ((float4*)(Y + (size_t)row * D_))[lane] = r;
}

// ---------------- weight transpose: Wt[n][k] = bf16(W[k][n]) ----------------
__global__ __launch_bounds__(256) void wtrans_kernel(const float* __restrict__ W,
                                                     unsigned short* __restrict__ Wt) {
    __shared__ float tile[64][65];
    int c0 = blockIdx.x * 64, r0 = blockIdx.y * 64, l = blockIdx.z;
    const float* src = W + (size_t)l * DD_;
    unsigned short* dst = Wt + (size_t)l * DD_;
    int tid = threadIdx.x;
#pragma unroll
    for (int rep = 0; rep < 16; ++rep) {
        int idx = rep * 256 + tid;
        int r = idx >> 6, c = idx & 63;
        tile[r][c] = src[(size_t)(r0 + r) * D_ + c0 + c];
    }
    __syncthreads();
#pragma unroll
    for (int rep = 0; rep < 16; ++rep) {
        int idx = rep * 256 + tid;
        int r2 = idx >> 6, c2 = idx & 63;
        dst[(size_t)(c0 + r2) * D_ + r0 + c2] = f2bf(tile[c2][r2]);
    }
}

// ---------------- MFMA GEMM: C[M,256] = A[M,256] @ W + bias (+res)(relu) ----
// A fp32 row-major; Wt bf16 [n][k] (pre-transposed). 128x128 tile, 4 waves.
template<bool RELU, bool RES>
__global__ __launch_bounds__(256) void gemm_mfma(
    const float* __restrict__ A, const unsigned short* __restrict__ Wt,
    const float* __restrict__ bias, const float* __restrict__ res,
    float* __restrict__ C) {
    __shared__ unsigned short As[128 * GS_];
    __shared__ unsigned short Ws[128 * GS_];
    int t = threadIdx.x, lane = t & 63, wv = t >> 6;
    int wm = wv >> 1, wn = wv & 1;
    int l15 = lane & 15, l4 = lane >> 4;
    int m0 = blockIdx.y * 128, n0 = blockIdx.x * 128;

    f32x4 acc[4][4];
#pragma unroll
    for (int m = 0; m < 4; ++m)
#pragma unroll
        for (int n = 0; n < 4; ++n)
            acc[m][n] = f32x4{0.f, 0.f, 0.f, 0.f};

    for (int k0 = 0; k0 < D_; k0 += 64) {
        // stage A: 128 rows x 64 k (fp32 -> bf16)
#pragma unroll
        for (int rep = 0; rep < 8; ++rep) {
            int idx = rep * 256 + t;
            int r = idx >> 4, c4 = (idx & 15) * 4;
            float4 a = *(const float4*)(A + (size_t)(m0 + r) * D_ + k0 + c4);
            unsigned* p = (unsigned*)&As[r * GS_ + c4];
            p[0] = pk2(a.x, a.y);
            p[1] = pk2(a.z, a.w);
        }
        // stage W: 128 n-rows x 64 k (bf16 16B copies)
#pragma unroll
        for (int rep = 0; rep < 4; ++rep) {
            int idx = rep * 256 + t;
            int r = idx >> 3, c8 = (idx & 7) * 8;
            *(i32x4*)&Ws[r * GS_ + c8] =
                *(const i32x4*)(Wt + (size_t)(n0 + r) * D_ + k0 + c8);
        }
        __syncthreads();
#pragma unroll
        for (int kk = 0; kk < 2; ++kk) {
            bf16x8 af[4], bf[4];
#pragma unroll
            for (int m = 0; m < 4; ++m)
                af[m] = *(const bf16x8*)&As[(wm*64 + m*16 + l15) * GS_ + kk*32 + l4*8];
#pragma unroll
            for (int n = 0; n < 4; ++n)
                bf[n] = *(const bf16x8*)&Ws[(wn*64 + n*16 + l15) * GS_ + kk*32 + l4*8];
#pragma unroll
            for (int m = 0; m < 4; ++m)
#pragma unroll
                for (int n = 0; n < 4; ++n)
                    acc[m][n] = __builtin_amdgcn_mfma_f32_16x16x32_bf16(af[m], bf[n], acc[m][n], 0, 0, 0);
        }
        __syncthreads();
    }
#pragma unroll
    for (int n = 0; n < 4; ++n) {
        int gn = n0 + wn*64 + n*16 + l15;
        float bn = bias[gn];
#pragma unroll
        for (int m = 0; m < 4; ++m) {
#pragma unroll
            for (int i = 0; i < 4; ++i) {
                int gm = m0 + wm*64 + m*16 + l4*4 + i;
                float v = acc[m][n][i] + bn;
                if (RES) v += res[(size_t)gm * D_ + gn];
                if (RELU) v = fmaxf(v, 0.f);
                C[(size_t)gm * D_ + gn] = v;
            }
        }
    }
}

// ---------------- MFMA attention ----------------
// one block per (h, b). NOTE: o may alias k (in-place): each block fully stages
// its K slice into LDS (then __syncthreads) before any o write; slices disjoint.
template<bool DEC>
__global__ __launch_bounds__(256) void attn_mfma(
    const float* __restrict__ q, const float* k,
    const float* __restrict__ v, const float* __restrict__ cm,
    float* o) {
    __shared__ unsigned short Ks[208 * KS_S];    // [kpos][dk]
    __shared__ unsigned short Vt[64 * VT_S];     // [dk][kpos]
    __shared__ unsigned short Ps[4 * 16 * VT_S]; // per-wave [qrow][kpos]
    int h = blockIdx.x, b = blockIdx.y;
    int tid = threadIdx.x, lane = tid & 63, wv = tid >> 6;
    int l15 = lane & 15, l4 = lane >> 4;
    size_t base = (size_t)(b * T_) * D_ + h * 64;

    for (int i = tid; i < T_ * 16; i += 256) {
        int r = i >> 4, c4 = (i & 15) << 2;
        float4 kv = *(const float4*)(k + base + (size_t)r * D_ + c4);
        int idx = r * KS_S + c4;
        *(unsigned*)&Ks[idx]     = pk2(kv.x, kv.y);
        *(unsigned*)&Ks[idx + 2] = pk2(kv.z, kv.w);
        float4 vv = *(const float4*)(v + base + (size_t)r * D_ + c4);
        Vt[(c4 + 0) * VT_S + r] = f2bf(vv.x);
        Vt[(c4 + 1) * VT_S + r] = f2bf(vv.y);
        Vt[(c4 + 2) * VT_S + r] = f2bf(vv.z);
        Vt[(c4 + 3) * VT_S + r] = f2bf(vv.w);
    }
    for (int i = tid; i < 8 * KS_S; i += 256) Ks[200 * KS_S + i] = 0;
    for (int i = tid; i < 64 * 32; i += 256) Vt[(i >> 5) * VT_S + 200 + (i & 31)] = 0;
    for (int i = tid; i < 64 * 24; i += 256) Ps[(i / 24) * VT_S + 208 + (i % 24)] = 0;
    __syncthreads();

    unsigned short* pw = &Ps[wv * 16 * VT_S];
    const f32x4 zero = {0.f, 0.f, 0.f, 0.f};

    for (int qt = wv; qt < 13; qt += 4) {
        int q0 = qt * 16;
        int qrow = q0 + l15;
        int qrc = qrow < T_ ? qrow : T_ - 1;
        const float* qp = q + base + (size_t)qrc * D_ + l4 * 8;
        float4 qa = *(const float4*)qp;
        float4 qb4 = *(const float4*)(qp + 4);
        float4 qc = *(const float4*)(qp + 32);
        float4 qd = *(const float4*)(qp + 36);
        frag8 aq0, aq1;
        aq0.u[0] = pk2(qa.x, qa.y);  aq0.u[1] = pk2(qa.z, qa.w);
        aq0.u[2] = pk2(qb4.x, qb4.y); aq0.u[3] = pk2(qb4.z, qb4.w);
        aq1.u[0] = pk2(qc.x, qc.y);  aq1.u[1] = pk2(qc.z, qc.w);
        aq1.u[2] = pk2(qd.x, qd.y);  aq1.u[3] = pk2(qd.z, qd.w);

        f32x4 S[13];
        float mx[4] = {-3e38f, -3e38f, -3e38f, -3e38f};
#pragma unroll
        for (int kt = 0; kt < 13; ++kt) {
            if (kt <= qt) {
                bf16x8 b0 = *(const bf16x8*)&Ks[(kt * 16 + l15) * KS_S + l4 * 8];
                bf16x8 b1 = *(const bf16x8*)&Ks[(kt * 16 + l15) * KS_S + 32 + l4 * 8];
                f32x4 acc = __builtin_amdgcn_mfma_f32_16x16x32_bf16(aq0.v, b0, zero, 0, 0, 0);
                acc = __builtin_amdgcn_mfma_f32_16x16x32_bf16(aq1.v, b1, acc, 0, 0, 0);
                f32x4 sv;
#pragma unroll
                for (int i = 0; i < 4; ++i) {
                    int kk = kt * 16 + l15;
                    int qr = q0 + l4 * 4 + i;
                    float s = acc[i] * 0.125f;
                    bool valid = (qr < T_) && (kk < T_);
                    if (!valid) s = -1e9f;
                    else {
                        if (kk > qr) s = -1e9f;  // mask BEFORE cm multiply (as reference)
                        if (DEC) s *= (1.0f + 0.5f * cm[((size_t)(b * T_) + qr) * T_ + kk]);
                    }
                    sv[i] = s;
                    mx[i] = fmaxf(mx[i], s);
                }
                S[kt] = sv;
            }
        }
#pragma unroll
        for (int i = 0; i < 4; ++i) {
            float m = mx[i];
            m = fmaxf(m, __shfl_xor(m, 1));
            m = fmaxf(m, __shfl_xor(m, 2));
            m = fmaxf(m, __shfl_xor(m, 4));
            m = fmaxf(m, __shfl_xor(m, 8));
            mx[i] = m;
        }
        float sum[4] = {0.f, 0.f, 0.f, 0.f};
#pragma unroll
        for (int kt = 0; kt < 13; ++kt) {
            if (kt <= qt) {
#pragma unroll
                for (int i = 0; i < 4; ++i) {
                    float e = __expf(S[kt][i] - mx[i]);
                    S[kt][i] = e;
                    sum[i] += e;
                }
            }
        }
#pragma unroll
        for (int i = 0; i < 4; ++i) {
            float s = sum[i];
            s += __shfl_xor(s, 1);
            s += __shfl_xor(s, 2);
            s += __shfl_xor(s, 4);
            s += __shfl_xor(s, 8);
            sum[i] = 1.f / s;
        }
#pragma unroll
        for (int kt = 0; kt < 13; ++kt) {
#pragma unroll
            for (int i = 0; i < 4; ++i)
                pw[(l4 * 4 + i) * VT_S + kt * 16 + l15] =
                    (kt <= qt) ? f2bf(S[kt][i] * sum[i]) : (unsigned short)0;
        }

        int lastcol = q0 + 15;
        int npv32 = (lastcol >> 5) + 1; if (npv32 > 7) npv32 = 7;
        bf16x8 pa[7];
#pragma unroll
        for (int t = 0; t < 7; ++t)
            if (t < npv32)
                pa[t] = *(const bf16x8*)&pw[l15 * VT_S + t * 32 + l4 * 8];

        f32x4 O[4];
#pragma unroll
        for (int dt = 0; dt < 4; ++dt) {
            f32x4 acc = zero;
#pragma unroll
            for (int t = 0; t < 7; ++t) {
                if (t < npv32) {
                    bf16x8 vb = *(const bf16x8*)&Vt[(dt * 16 + l15) * VT_S + t * 32 + l4 * 8];
                    acc = __builtin_amdgcn_mfma_f32_16x16x32_bf16(pa[t], vb, acc, 0, 0, 0);
                }
            }
            O[dt] = acc;
        }
#pragma unroll
        for (int dt = 0; dt < 4; ++dt) {
#pragma unroll
            for (int i = 0; i < 4; ++i) {
                int qr = q0 + l4 * 4 + i;
                if (qr < T_)
                    o[base + (size_t)qr * D_ + dt * 16 + l15] = O[dt][i];
            }
        }
    }
}

// ---------------- cov ----------------
__global__ void rowmean_kernel(const float* __restrict__ Z, float* __restrict__ m) {
    int row = blockIdx.x, lane = threadIdx.x;
    float4 x = ((const float4*)(Z + (size_t)row * D_))[lane];
    float s = wave_sum(x.x + x.y + x.z + x.w);
    if (lane == 0) m[row] = s * (1.f / D_);
}

// per-batch MFMA cov: cm[b,t,s] = min(Zc_t . Zc_s / 255, 3), lower triangle + mirror
__global__ __launch_bounds__(512) void cov_mfma(const float* __restrict__ Z,
                                                const float* __restrict__ rm,
                                                float* __restrict__ cm) {
    __shared__ unsigned short Zb[208 * ZS_];   // [t][d] bf16, zero-padded rows 200..207
    int b = blockIdx.x;
    int tid = threadIdx.x, lane = tid & 63, wv = tid >> 6;
    int l15 = lane & 15, l4 = lane >> 4;

    for (int i = tid; i < T_ * 64; i += 512) {
        int t = i >> 6, c4 = (i & 63) << 2;
        float4 z = *(const float4*)(Z + ((size_t)b * T_ + t) * D_ + c4);
        float m = rm[b * T_ + t];
        unsigned* p = (unsigned*)&Zb[t * ZS_ + c4];
        p[0] = pk2(z.x - m, z.y - m);
        p[1] = pk2(z.z - m, z.w - m);
    }
    for (int i = tid; i < 8 * ZS_; i += 512) Zb[T_ * ZS_ + i] = 0;
    __syncthreads();

    for (int job = wv; job < 91; job += 8) {
        int ti = 0;
        while ((ti + 1) * (ti + 2) / 2 <= job) ++ti;
        int tj = job - ti * (ti + 1) / 2;
        f32x4 acc = {0.f, 0.f, 0.f, 0.f};
#pragma unroll
        for (int s = 0; s < 8; ++s) {
            bf16x8 a  = *(const bf16x8*)&Zb[(ti * 16 + l15) * ZS_ + s * 32 + l4 * 8];
            bf16x8 bb = *(const bf16x8*)&Zb[(tj * 16 + l15) * ZS_ + s * 32 + l4 * 8];
            acc = __builtin_amdgcn_mfma_f32_16x16x32_bf16(a, bb, acc, 0, 0, 0);
        }
#pragma unroll
        for (int i = 0; i < 4; ++i) {
            int t = ti * 16 + l4 * 4 + i, s2 = tj * 16 + l15;
            float vv = fminf(acc[i] * (1.f / 255.f), 3.0f);
            if (t < T_ && s2 < T_) {
                cm[((size_t)b * T_ + t) * T_ + s2] = vv;
                cm[((size_t)b * T_ + s2) * T_ + t] = vv;
            }
        }
    }
}

extern "C" void kernel_launch(void* const* d_in, const int* in_sizes, int n_in,
                              void* d_out, int out_size, void* d_ws, size_t ws_size,
                              hipStream_t stream) {
    const int*   log_seqs = (const int*)  d_in[0];
    const float* item_tab = (const float*)d_in[1];
    const float* pos_tab  = (const float*)d_in[2];
    const float* ln1_s = (const float*)d_in[3];
    const float* ln1_b = (const float*)d_in[4];
    const float* Wq = (const float*)d_in[5];
    const float* bq = (const float*)d_in[6];
    const float* Wk = (const float*)d_in[7];
    const float* bk = (const float*)d_in[8];
    const float* Wv = (const float*)d_in[9];
    const float* bv = (const float*)d_in[10];
    const float* Wo = (const float*)d_in[11];
    const float* bo = (const float*)d_in[12];
    const float* ln2_s = (const float*)d_in[13];
    const float* ln2_b = (const float*)d_in[14];
    const float* W1 = (const float*)d_in[15];
    const float* b1 = (const float*)d_in[16];
    const float* W2 = (const float*)d_in[17];
    const float* b2 = (const float*)d_in[18];
    const float* last_s = (const float*)d_in[19];
    const float* last_b = (const float*)d_in[20];

    float* ws = (float*)d_ws;
    const size_t NTD = (size_t)BT_ * D_;
    float* s0    = ws;              // seqs / layer-3 out
    float* s1    = s0 + NTD;        // causal_z / layer-2 out
    float* Qn    = s1 + NTD;        // ln1 output (residual)
    float* qb    = Qn + NTD;        // q, then attn-residual sum s
    float* kb    = qb + NTD;        // k, then attn out (in-place), then y
    float* vb    = kb + NTD;        // v, then ffn tmp
    float* cmask = vb + NTD;        // B*T*T
    float* rmean = cmask + (size_t)B_ * T_ * T_;
    unsigned short* wtb = (unsigned short*)(rmean + BT_);  // 24 x 256x256 bf16 W^T

    unsigned short* wtq = wtb;
    unsigned short* wtk = wtb + 4 * (size_t)DD_;
    unsigned short* wtv = wtb + 8 * (size_t)DD_;
    unsigned short* wto = wtb + 12 * (size_t)DD_;
    unsigned short* wt1 = wtb + 16 * (size_t)DD_;
    unsigned short* wt2 = wtb + 20 * (size_t)DD_;

    // one-time weight transposes (fp32 -> bf16 W^T[n][k])
    dim3 tg(4, 4, 4);
    wtrans_kernel<<<tg, 256, 0, stream>>>(Wq, wtq);
    wtrans_kernel<<<tg, 256, 0, stream>>>(Wk, wtk);
    wtrans_kernel<<<tg, 256, 0, stream>>>(Wv, wtv);
    wtrans_kernel<<<tg, 256, 0, stream>>>(Wo, wto);
    wtrans_kernel<<<tg, 256, 0, stream>>>(W1, wt1);
    wtrans_kernel<<<tg, 256, 0, stream>>>(W2, wt2);

    dim3 gg(2, 400);   // N/128, M/128

    auto encoder = [&](const float* X, float* OUT, int i, const float* cmp) {
        ln_kernel<<<BT_, 64, 0, stream>>>(X, ln1_s + i*D_, ln1_b + i*D_, Qn);
        gemm_mfma<false,false><<<gg, 256, 0, stream>>>(Qn, wtq + (size_t)i*DD_, bq + i*D_, nullptr, qb);
        gemm_mfma<false,false><<<gg, 256, 0, stream>>>(X,  wtk + (size_t)i*DD_, bk + i*D_, nullptr, kb);
        gemm_mfma<false,false><<<gg, 256, 0, stream>>>(X,  wtv + (size_t)i*DD_, bv + i*D_, nullptr, vb);
        // attention writes output in-place over kb
        if (cmp) attn_mfma<true ><<<dim3(H_, B_), 256, 0, stream>>>(qb, kb, vb, cmp, kb);
        else     attn_mfma<false><<<dim3(H_, B_), 256, 0, stream>>>(qb, kb, vb, nullptr, kb);
        gemm_mfma<false,true><<<gg, 256, 0, stream>>>(kb, wto + (size_t)i*DD_, bo + i*D_, Qn, qb);
        ln_kernel<<<BT_, 64, 0, stream>>>(qb, ln2_s + i*D_, ln2_b + i*D_, kb);
        gemm_mfma<true,false><<<gg, 256, 0, stream>>>(kb, wt1 + (size_t)i*DD_, b1 + i*D_, nullptr, vb);
        gemm_mfma<false,true><<<gg, 256, 0, stream>>>(vb, wt2 + (size_t)i*DD_, b2 + i*D_, kb, OUT);
    };

    embed_kernel<<<BT_, 64, 0, stream>>>(log_seqs, item_tab, pos_tab, s0);

    // causal loop applies each layer to ORIGINAL seqs -> only layer 1 survives
    encoder(s0, s1, 1, nullptr);

    rowmean_kernel<<<BT_, 64, 0, stream>>>(s1, rmean);
    cov_mfma<<<B_, 512, 0, stream>>>(s1, rmean, cmask);

    encoder(s0, s1, 2, cmask);
    encoder(s1, s0, 3, cmask);

    ln_kernel<<<BT_, 64, 0, stream>>>(s0, last_s, last_b, (float*)d_out);
}